// Round 1
// baseline (417.039 us; speedup 1.0000x reference)
//
#include <hip/hip_runtime.h>

// Inverse 2-tap DWT (Haar-style). Algebra of the reference collapses to:
//   y[2m]   = a_m*lo[1] + d_m*hi[1]
//   y[2m+1] = a_m*lo[0] + d_m*hi[0]
// with x stored as interleaved (a,d) pairs -> pure elementwise float2->float2
// map at identical pair index. Memory-bound: 256 MiB in + 256 MiB out.

__global__ void __launch_bounds__(256) idwt1d_kernel(
    const float4* __restrict__ x,   // two (a,d) pairs per element
    float4* __restrict__ out,       // two (even,odd) output pairs per element
    const float* __restrict__ lo,   // 2 floats
    const float* __restrict__ hi,   // 2 floats
    int n4)                         // number of float4 elements
{
    int i = blockIdx.x * blockDim.x + threadIdx.x;
    if (i >= n4) return;

    // Uniform broadcast loads (L2/scalar cached).
    const float l0 = lo[0], l1 = lo[1];
    const float h0 = hi[0], h1 = hi[1];

    float4 v = x[i];
    float4 o;
    o.x = v.x * l1 + v.y * h1;  // even output of pair 2i
    o.y = v.x * l0 + v.y * h0;  // odd  output of pair 2i
    o.z = v.z * l1 + v.w * h1;  // even output of pair 2i+1
    o.w = v.z * l0 + v.w * h0;  // odd  output of pair 2i+1
    out[i] = o;
}

extern "C" void kernel_launch(void* const* d_in, const int* in_sizes, int n_in,
                              void* d_out, int out_size, void* d_ws, size_t ws_size,
                              hipStream_t stream) {
    const float4* x  = (const float4*)d_in[0];
    const float*  lo = (const float*)d_in[1];
    const float*  hi = (const float*)d_in[2];
    float4* out = (float4*)d_out;

    const int n4 = in_sizes[0] / 4;  // 67,108,864 / 4 = 16,777,216
    const int block = 256;
    const int grid = (n4 + block - 1) / block;
    idwt1d_kernel<<<grid, block, 0, stream>>>(x, out, lo, hi, n4);
}